// Round 10
// baseline (95.665 us; speedup 1.0000x reference)
//
#include <hip/hip_runtime.h>

#define NQ 4
#define DIM 16
#define E 4   // batch elements per thread

// Split design (round 10):
//  qlayer_prep (1 block): build weight unitary W -> folded symmetric table
//    G (10x10 float4) -> d_ws (1.6 KB).
//  qlayer_main: NO LDS, NO barriers. G read straight from global with
//    uniform compile-time indices -> s_load_dwordx4 (scalar pipe, SGPR
//    destination, compiler hoists freely). ext_vector float4 math so the
//    backend can emit v_pk_fma_f32 (packed fp32, 2x issue).
//    o_q = sum_ac hp_ac * (sum_bd llp_bd * G_q[ac][bd]).

typedef __attribute__((ext_vector_type(4))) float fv4;

constexpr int PA[10] = {0,0,0,0,1,1,1,2,2,3};
constexpr int PC[10] = {0,1,2,3,1,2,3,2,3,3};

__global__ void __launch_bounds__(128)
qlayer_prep(const float* __restrict__ weights, float4* __restrict__ gw)
{
    __shared__ __align__(16) float2 WT[DIM][DIM];   // WT[j][i] = W[i][j]

    // ---- threads 0..15: build W columns (verified R1-R9) ----
    if (threadIdx.x < DIM) {
        const int k = threadIdx.x;
        float sre[DIM], sim[DIM];
#pragma unroll
        for (int i = 0; i < DIM; ++i) { sre[i] = (i == k) ? 1.f : 0.f; sim[i] = 0.f; }
#pragma unroll
        for (int l = 0; l < 3; ++l) {
#pragma unroll
            for (int p = 0; p < NQ; ++p) {
                const float h = 0.5f * weights[l * NQ + p];
                const float s = __sinf(h), c = __cosf(h);
                const int mask = 1 << (NQ - 1 - p);
#pragma unroll
                for (int i = 0; i < DIM; ++i) {
                    if (i & mask) continue;
                    const int jj = i | mask;
                    const float ar = sre[i], ai = sim[i];
                    const float br = sre[jj], bi = sim[jj];
                    sre[i]  = c * ar + s * bi;
                    sim[i]  = c * ai - s * br;
                    sre[jj] = c * br + s * ai;
                    sim[jj] = c * bi - s * ar;
                }
            }
#pragma unroll
            for (int p = 0; p < NQ; ++p) {
                const int t = (p + 1) % NQ;
                float tr[DIM], ti[DIM];
#pragma unroll
                for (int i = 0; i < DIM; ++i) {
                    const int src = i ^ ((((i >> (NQ - 1 - p)) & 1)) << (NQ - 1 - t));
                    tr[i] = sre[src]; ti[i] = sim[src];
                }
#pragma unroll
                for (int i = 0; i < DIM; ++i) { sre[i] = tr[i]; sim[i] = ti[i]; }
            }
        }
#pragma unroll
        for (int i = 0; i < DIM; ++i) WT[k][i] = make_float2(sre[i], sim[i]);
    }
    __syncthreads();

    // ---- threads 0..99: fold into G, write to global (verified R2-R9) ----
    if (threadIdx.x < 100) {
        const int ac = threadIdx.x / 10, bd = threadIdx.x % 10;
        const int a = PA[ac], c = PC[ac], b = PA[bd], d = PC[bd];

        auto evalS = [&](int j, int k, float* sv) {
            float ar[4] = {0,0,0,0}, ai[4] = {0,0,0,0};
#pragma unroll
            for (int i = 0; i < DIM; ++i) {
                const float2 wj = WT[j][i], wk = WT[k][i];
                const float pr = wj.x * wk.x + wj.y * wk.y;
                const float pi = wj.x * wk.y - wj.y * wk.x;
#pragma unroll
                for (int q = 0; q < 4; ++q) {
                    const float s = ((i >> (3 - q)) & 1) ? -1.f : 1.f;
                    ar[q] += s * pr; ai[q] += s * pi;
                }
            }
            const int m = (__builtin_popcount(j) - __builtin_popcount(k)) & 3;
#pragma unroll
            for (int q = 0; q < 4; ++q)
                sv[q] = (m == 0) ? ar[q] : (m == 1) ? -ai[q] : (m == 2) ? -ar[q] : ai[q];
        };

        float s1[4], s2[4];
        evalS(4 * a + b, 4 * c + d, s1);
        evalS(4 * a + d, 4 * c + b, s2);
        const float u = ((a < c) ? 2.f : 1.f) * ((b < d) ? 1.f : 0.5f);
        gw[ac * 10 + bd] = make_float4(u * (s1[0] + s2[0]), u * (s1[1] + s2[1]),
                                       u * (s1[2] + s2[2]), u * (s1[3] + s2[3]));
    }
}

__global__ void __launch_bounds__(256)
qlayer_main(const float4* __restrict__ x,
            const fv4* __restrict__ gw,
            fv4* __restrict__ out, int B)
{
    const int tid  = threadIdx.x;
    const int base = blockIdx.x * (256 * E) + tid;

    float hh[E][4], llp[E][10];
    fv4 o[E];

#pragma unroll
    for (int e = 0; e < E; ++e) {
        const int gi = base + e * 256;
        const float4 xv = (gi < B) ? x[gi] : make_float4(0.f, 0.f, 0.f, 0.f);
        const float s0 = __sinf(0.5f * xv.x), c0 = __cosf(0.5f * xv.x);
        const float s1 = __sinf(0.5f * xv.y), c1 = __cosf(0.5f * xv.y);
        const float s2 = __sinf(0.5f * xv.z), c2 = __cosf(0.5f * xv.z);
        const float s3 = __sinf(0.5f * xv.w), c3 = __cosf(0.5f * xv.w);
        hh[e][0] = c0 * c1; hh[e][1] = c0 * s1; hh[e][2] = s0 * c1; hh[e][3] = s0 * s1;
        const float ll[4] = {c2 * c3, c2 * s3, s2 * c3, s2 * s3};
#pragma unroll
        for (int p = 0; p < 10; ++p) llp[e][p] = ll[PA[p]] * ll[PC[p]];
        o[e] = (fv4)(0.f);
    }

#pragma unroll
    for (int ac = 0; ac < 10; ++ac) {
        // Uniform address, compile-time index, read-only __restrict__ memory
        // -> scalar loads (s_load_dwordx4) the compiler can hoist cheaply.
        fv4 g[10];
#pragma unroll
        for (int bd = 0; bd < 10; ++bd) g[bd] = gw[ac * 10 + bd];
#pragma unroll
        for (int e = 0; e < E; ++e) {
            fv4 t = (fv4)(0.f);
#pragma unroll
            for (int bd = 0; bd < 10; ++bd)
                t += g[bd] * llp[e][bd];                 // v_pk_fma_f32 pairs
            o[e] += t * (hh[e][PA[ac]] * hh[e][PC[ac]]);
        }
    }

#pragma unroll
    for (int e = 0; e < E; ++e) {
        const int gi = base + e * 256;
        if (gi < B) out[gi] = o[e];
    }
}

extern "C" void kernel_launch(void* const* d_in, const int* in_sizes, int n_in,
                              void* d_out, int out_size, void* d_ws, size_t ws_size,
                              hipStream_t stream)
{
    const float4* x = (const float4*)d_in[0];
    const float* w  = (const float*)d_in[1];
    fv4* out        = (fv4*)d_out;
    float4* gw      = (float4*)d_ws;     // 100 * 16 B = 1.6 KB
    const int B = in_sizes[0] / NQ;

    qlayer_prep<<<1, 128, 0, stream>>>(w, gw);

    const int block = 256;
    const int perBlock = block * E;
    const int grid = (B + perBlock - 1) / perBlock;
    qlayer_main<<<grid, block, 0, stream>>>(x, (const fv4*)gw, out, B);
}

// Round 11
// 83.961 us; speedup vs baseline: 1.1394x; 1.1394x over previous
//
#include <hip/hip_runtime.h>

#define NQ 4
#define DIM 16

// Split design (round 11):
//  qlayer_prep (1 block): build weight unitary W -> folded symmetric table
//    G (10x10 float4) -> d_ws (1.6 KB). Unchanged (verified R8-R10).
//  qlayer_main: E=1, minimal live state (~35 floats) -> 8 waves/SIMD TLP.
//    G staged to LDS (wave-uniform broadcast ds_read_b128, conflict-free).
//    o_q = sum_ac hp_ac * (sum_bd llp_bd * G_q[ac][bd]).

typedef __attribute__((ext_vector_type(4))) float fv4;

constexpr int PA[10] = {0,0,0,0,1,1,1,2,2,3};
constexpr int PC[10] = {0,1,2,3,1,2,3,2,3,3};

__global__ void __launch_bounds__(128)
qlayer_prep(const float* __restrict__ weights, float4* __restrict__ gw)
{
    __shared__ __align__(16) float2 WT[DIM][DIM];   // WT[j][i] = W[i][j]

    // ---- threads 0..15: build W columns (verified R1-R10) ----
    if (threadIdx.x < DIM) {
        const int k = threadIdx.x;
        float sre[DIM], sim[DIM];
#pragma unroll
        for (int i = 0; i < DIM; ++i) { sre[i] = (i == k) ? 1.f : 0.f; sim[i] = 0.f; }
#pragma unroll
        for (int l = 0; l < 3; ++l) {
#pragma unroll
            for (int p = 0; p < NQ; ++p) {
                const float h = 0.5f * weights[l * NQ + p];
                const float s = __sinf(h), c = __cosf(h);
                const int mask = 1 << (NQ - 1 - p);
#pragma unroll
                for (int i = 0; i < DIM; ++i) {
                    if (i & mask) continue;
                    const int jj = i | mask;
                    const float ar = sre[i], ai = sim[i];
                    const float br = sre[jj], bi = sim[jj];
                    sre[i]  = c * ar + s * bi;
                    sim[i]  = c * ai - s * br;
                    sre[jj] = c * br + s * ai;
                    sim[jj] = c * bi - s * ar;
                }
            }
#pragma unroll
            for (int p = 0; p < NQ; ++p) {
                const int t = (p + 1) % NQ;
                float tr[DIM], ti[DIM];
#pragma unroll
                for (int i = 0; i < DIM; ++i) {
                    const int src = i ^ ((((i >> (NQ - 1 - p)) & 1)) << (NQ - 1 - t));
                    tr[i] = sre[src]; ti[i] = sim[src];
                }
#pragma unroll
                for (int i = 0; i < DIM; ++i) { sre[i] = tr[i]; sim[i] = ti[i]; }
            }
        }
#pragma unroll
        for (int i = 0; i < DIM; ++i) WT[k][i] = make_float2(sre[i], sim[i]);
    }
    __syncthreads();

    // ---- threads 0..99: fold into G, write to global (verified R2-R10) ----
    if (threadIdx.x < 100) {
        const int ac = threadIdx.x / 10, bd = threadIdx.x % 10;
        const int a = PA[ac], c = PC[ac], b = PA[bd], d = PC[bd];

        auto evalS = [&](int j, int k, float* sv) {
            float ar[4] = {0,0,0,0}, ai[4] = {0,0,0,0};
#pragma unroll
            for (int i = 0; i < DIM; ++i) {
                const float2 wj = WT[j][i], wk = WT[k][i];
                const float pr = wj.x * wk.x + wj.y * wk.y;
                const float pi = wj.x * wk.y - wj.y * wk.x;
#pragma unroll
                for (int q = 0; q < 4; ++q) {
                    const float s = ((i >> (3 - q)) & 1) ? -1.f : 1.f;
                    ar[q] += s * pr; ai[q] += s * pi;
                }
            }
            const int m = (__builtin_popcount(j) - __builtin_popcount(k)) & 3;
#pragma unroll
            for (int q = 0; q < 4; ++q)
                sv[q] = (m == 0) ? ar[q] : (m == 1) ? -ai[q] : (m == 2) ? -ar[q] : ai[q];
        };

        float s1[4], s2[4];
        evalS(4 * a + b, 4 * c + d, s1);
        evalS(4 * a + d, 4 * c + b, s2);
        const float u = ((a < c) ? 2.f : 1.f) * ((b < d) ? 1.f : 0.5f);
        gw[ac * 10 + bd] = make_float4(u * (s1[0] + s2[0]), u * (s1[1] + s2[1]),
                                       u * (s1[2] + s2[2]), u * (s1[3] + s2[3]));
    }
}

__global__ void __launch_bounds__(256)
qlayer_main(const float4* __restrict__ x,
            const float4* __restrict__ gw,
            fv4* __restrict__ out, int B)
{
    __shared__ __align__(16) fv4 G4[100];
    if (threadIdx.x < 100) G4[threadIdx.x] = ((const fv4*)gw)[threadIdx.x];
    __syncthreads();

    const int gi = blockIdx.x * 256 + threadIdx.x;
    if (gi >= B) return;

    const float4 xv = x[gi];
    const float s0 = __sinf(0.5f * xv.x), c0 = __cosf(0.5f * xv.x);
    const float s1 = __sinf(0.5f * xv.y), c1 = __cosf(0.5f * xv.y);
    const float s2 = __sinf(0.5f * xv.z), c2 = __cosf(0.5f * xv.z);
    const float s3 = __sinf(0.5f * xv.w), c3 = __cosf(0.5f * xv.w);

    const float hh[4] = {c0 * c1, c0 * s1, s0 * c1, s0 * s1};
    const float ll[4] = {c2 * c3, c2 * s3, s2 * c3, s2 * s3};
    float llp[10];
#pragma unroll
    for (int p = 0; p < 10; ++p) llp[p] = ll[PA[p]] * ll[PC[p]];

    fv4 o = (fv4)(0.f);
#pragma unroll
    for (int ac = 0; ac < 10; ++ac) {
        fv4 t = (fv4)(0.f);
#pragma unroll
        for (int bd = 0; bd < 10; ++bd)
            t += G4[ac * 10 + bd] * llp[bd];            // broadcast ds_read_b128
        o += t * (hh[PA[ac]] * hh[PC[ac]]);
    }

    out[gi] = o;
}

extern "C" void kernel_launch(void* const* d_in, const int* in_sizes, int n_in,
                              void* d_out, int out_size, void* d_ws, size_t ws_size,
                              hipStream_t stream)
{
    const float4* x = (const float4*)d_in[0];
    const float* w  = (const float*)d_in[1];
    fv4* out        = (fv4*)d_out;
    float4* gw      = (float4*)d_ws;     // 100 * 16 B = 1.6 KB
    const int B = in_sizes[0] / NQ;

    qlayer_prep<<<1, 128, 0, stream>>>(w, gw);

    const int block = 256;
    const int grid = (B + block - 1) / block;    // 4096 blocks, E=1
    qlayer_main<<<grid, block, 0, stream>>>(x, gw, out, B);
}